// Round 1
// baseline (236.781 us; speedup 1.0000x reference)
//
#include <hip/hip_runtime.h>
#include <math.h>

// Problem constants (reference: B=4, T=2048, C=1024, H=16, d=64)
#define BB   4
#define TT   2048
#define CC   1024
#define HH   16
#define DD   64
#define MM   (BB*TT)     // 8192 rows
#define NQKV (3*CC)      // 3072
#define LCH  128         // attention chunk length
#define NCH  (TT/LCH)    // 16 chunks per (b,h)
#define EPSF 1e-6f

// LDS strides (in shorts) for attention kernels — padded to break bank aliasing
#define QKST 72          // Q/K tile row stride
#define PST  136         // P tile row stride
#define VTST 136         // V-transposed tile row stride

typedef __bf16 bf16x8 __attribute__((ext_vector_type(8)));
typedef float  floatx4 __attribute__((ext_vector_type(4)));

__device__ __forceinline__ unsigned short f2bf(float f) {
  union { float f; unsigned int u; } v; v.f = f;
  unsigned int r = v.u + 0x7fffu + ((v.u >> 16) & 1u); // RNE
  return (unsigned short)(r >> 16);
}
__device__ __forceinline__ float bf2f(unsigned short s) {
  union { unsigned int u; float f; } v; v.u = ((unsigned int)s) << 16;
  return v.f;
}
__device__ __forceinline__ float featmap(float v) {
  // elu(v)+1
  return v > 0.f ? v + 1.f : __expf(v);
}
// async global->LDS, 16B per lane; LDS dest = wave-uniform base + lane*16
__device__ __forceinline__ void gld_lds_b128(const unsigned short* g, unsigned short* l) {
  __builtin_amdgcn_global_load_lds(
      (const __attribute__((address_space(1))) unsigned int*)g,
      (__attribute__((address_space(3))) unsigned int*)l, 16, 0, 0);
}

// ---------------- prep: x->bf16 + both weight transposes, one kernel ----------------
__device__ __forceinline__ void transpose_cvt_body(const float* __restrict__ W,
                                                   unsigned short* __restrict__ out,
                                                   int R, int Cc, int bx32, int by32, int tid) {
  __shared__ float tile[32][33];
  int tx = tid & 31, ty = tid >> 5;  // 32 x 8
  int bx = bx32 * 32, by = by32 * 32;
  #pragma unroll
  for (int i = ty; i < 32; i += 8)
    tile[i][tx] = W[(size_t)(by + i) * Cc + bx + tx];
  __syncthreads();
  #pragma unroll
  for (int i = ty; i < 32; i += 8)
    out[(size_t)(bx + i) * R + by + tx] = f2bf(tile[tx][i]);
}

// grid: [0,8192) cvt_x | [8192,11264) W_attn transpose | [11264,12288) W_proj transpose
__global__ __launch_bounds__(256) void prep_kernel(
    const float* __restrict__ x, unsigned short* __restrict__ xb,
    const float* __restrict__ Wa, unsigned short* __restrict__ WaT,
    const float* __restrict__ Wp, unsigned short* __restrict__ WpT) {
  int blk = blockIdx.x, tid = threadIdx.x;
  if (blk < 8192) {
    int i = (blk * 256 + tid) * 4;
    float4 f = *(const float4*)(x + i);
    ushort4 o;
    o.x = f2bf(f.x); o.y = f2bf(f.y); o.z = f2bf(f.z); o.w = f2bf(f.w);
    *(ushort4*)(xb + i) = o;
  } else if (blk < 8192 + 3072) {
    int t = blk - 8192;                       // 96 x 32
    transpose_cvt_body(Wa, WaT, CC, NQKV, t % 96, t / 96, tid);
  } else {
    int t = blk - 11264;                      // 32 x 32
    transpose_cvt_body(Wp, WpT, CC, CC, t % 32, t / 32, tid);
  }
}

// ============== MFMA GEMM core: 128x128 tile, BK=64 (R6 known-good shape) ==========
// Used by gemm_proj only (N=1024 -> 256^2 tiles would leave half the CUs idle).
#define GEMM_K_LOOP(A_, Bt_, K_)                                                 \
  __shared__ __align__(16) unsigned short As[128 * 64];                          \
  __shared__ __align__(16) unsigned short Bs[128 * 64];                          \
  int tid = threadIdx.x;                                                         \
  int wave = tid >> 6, lane = tid & 63;                                          \
  int lr = lane & 15, lq = lane >> 4;                                            \
  int m0 = blockIdx.y * 128, n0 = blockIdx.x * 128;                              \
  int wm = (wave >> 1) * 64, wn = (wave & 1) * 64;                               \
  int lrow = lane >> 3;                 /* 0..7: row within 8-row chunk */       \
  int lk = (lane & 7) ^ lrow;           /* swizzled source k-chunk */            \
  int rbase = wave * 32;                                                         \
  const unsigned short* gA = A_ + (size_t)(m0 + rbase + lrow) * K_ + lk * 8;     \
  const unsigned short* gB = Bt_ + (size_t)(n0 + rbase + lrow) * K_ + lk * 8;    \
  unsigned short* lA = As + rbase * 64;                                          \
  unsigned short* lB = Bs + rbase * 64;                                          \
  floatx4 acc[4][4] = {};                                                        \
  for (int k0 = 0; k0 < K_; k0 += 64) {                                          \
    __syncthreads(); /* prior frag reads done before overwrite */                \
    _Pragma("unroll")                                                            \
    for (int g = 0; g < 4; g++) {                                                \
      gld_lds_b128(gA + k0 + (size_t)g * 8 * K_, lA + g * 512);                  \
      gld_lds_b128(gB + k0 + (size_t)g * 8 * K_, lB + g * 512);                  \
    }                                                                            \
    __syncthreads(); /* staged data visible */                                   \
    _Pragma("unroll")                                                            \
    for (int kk = 0; kk < 2; kk++) {                                             \
      bf16x8 an[4], bm[4];                                                       \
      _Pragma("unroll")                                                          \
      for (int i = 0; i < 4; i++)                                                \
        an[i] = *(const bf16x8*)&Bs[(wn + i * 16 + lr) * 64 + ((((kk << 2) + lq) ^ (lr & 7)) << 3)]; \
      _Pragma("unroll")                                                          \
      for (int j = 0; j < 4; j++)                                                \
        bm[j] = *(const bf16x8*)&As[(wm + j * 16 + lr) * 64 + ((((kk << 2) + lq) ^ (lr & 7)) << 3)]; \
      _Pragma("unroll")                                                          \
      for (int i = 0; i < 4; i++)                                                \
        _Pragma("unroll")                                                        \
        for (int j = 0; j < 4; j++)                                              \
          acc[i][j] = __builtin_amdgcn_mfma_f32_16x16x32_bf16(an[i], bm[j], acc[i][j], 0, 0, 0); \
    }                                                                            \
  }

// ---------------- GEMM 1: qkv = x @ W_attn + b, split + feature map ----------------
// NEW (R9): 256x256 tile, BK=32, 512 threads / 8 waves (2M x 4N), 4-slot LDS ring
// (128 KiB dynamic), counted vmcnt(8) pipeline (T3+T4), setprio around MFMA (T5),
// source-side chunk swizzle (T2-equivalent, LDS dest stays linear for gld_lds).
// Ring safety: while computing slot t&3 we stage K-tile t+3 -> slot (t+3)&3, whose
// last reader (K-tile t-1) finished >= 2 boundary barriers ago. vmcnt(8) at each
// K-tile boundary guarantees K-tile t+1 landed while K-tiles t+2,t+3 stay in flight.
// Math is bit-identical to the old kernel (same K summation order in 32-chunks).
#define BKQ   32
#define QSLOT (256 * BKQ)   // shorts per ring slot = 8192
#define NT_Q  (CC / BKQ)    // 32 K-tiles

__global__ __launch_bounds__(512, 2) void gemm_qkv_kernel(
    const unsigned short* __restrict__ A, const unsigned short* __restrict__ Bt,
    const float* __restrict__ bias,
    unsigned short* __restrict__ qh, unsigned short* __restrict__ kh,
    unsigned short* __restrict__ vh) {
  extern __shared__ __align__(16) unsigned short lds[];
  unsigned short* Asr = lds;                 // [4][256][32]
  unsigned short* Bsr = lds + 4 * QSLOT;     // [4][256][32]

  const int tid = threadIdx.x;
  const int wave = tid >> 6, lane = tid & 63;
  const int lr = lane & 15, lq = lane >> 4;
  const int m0 = blockIdx.y * 256, n0 = blockIdx.x * 256;
  const int wm = (wave >> 2) * 128, wn = (wave & 3) * 64;

  // staging: wave stages rows [wave*16, +16) (+128 for 2nd load); lane l covers
  // row wave*16 + (l>>2), LDS chunk l&3 (linear dest). Global source chunk is
  // pre-swizzled: cs = (l&3) ^ ((row>>1)&3), with (row>>1)&3 == (l>>3)&3.
  const int srow = wave * 16 + (lane >> 2);
  const int cs = (lane & 3) ^ ((lane >> 3) & 3);
  const unsigned short* gA = A  + (size_t)(m0 + srow) * CC + cs * 8;
  const unsigned short* gB = Bt + (size_t)(n0 + srow) * CC + cs * 8;
  unsigned short* const stA = Asr + wave * 512;   // wave-uniform LDS dest base
  unsigned short* const stB = Bsr + wave * 512;

  // reader: wants global chunk lq at row -> reads LDS chunk lq ^ ((row>>1)&3);
  // row = (wm|wn) + frag*16 + lr so (row>>1)&3 == (lr>>1)&3. Bijective over the
  // 16-row x 4-chunk group -> conflict-free ds_read_b128.
  const int chunk = lq ^ ((lr >> 1) & 3);
  const int roA = (wm + lr) * BKQ + chunk * 8;
  const int roB = (wn + lr) * BKQ + chunk * 8;

  floatx4 acc[4][8] = {};   // [n-frag][m-frag], transposed-C convention

#define QSTAGE_A(tt) do {                                      \
    const unsigned short* g_ = gA + (tt) * BKQ;                \
    unsigned short* d_ = stA + ((tt) & 3) * QSLOT;             \
    gld_lds_b128(g_, d_);                                      \
    gld_lds_b128(g_ + (size_t)128 * CC, d_ + 128 * BKQ);       \
  } while (0)
#define QSTAGE_B(tt) do {                                      \
    const unsigned short* g_ = gB + (tt) * BKQ;                \
    unsigned short* d_ = stB + ((tt) & 3) * QSLOT;             \
    gld_lds_b128(g_, d_);                                      \
    gld_lds_b128(g_ + (size_t)128 * CC, d_ + 128 * BKQ);       \
  } while (0)

  // prologue: K-tiles 0,1,2 issued (12 loads/thread); wait K0 (oldest 4), keep 8 in flight
  QSTAGE_A(0); QSTAGE_B(0);
  QSTAGE_A(1); QSTAGE_B(1);
  QSTAGE_A(2); QSTAGE_B(2);
  asm volatile("s_waitcnt vmcnt(8)" ::: "memory");
  __builtin_amdgcn_s_barrier();

  #pragma unroll 4
  for (int t = 0; t < NT_Q; ++t) {
    const unsigned short* sA = Asr + (t & 3) * QSLOT + roA;
    const unsigned short* sB = Bsr + (t & 3) * QSLOT + roB;
    bf16x8 an[4], bm[4], bm2[4];
    // ---- phase 1: read B-frags + first half of A-frags, stage A(t+3), 16 MFMA
    #pragma unroll
    for (int i = 0; i < 4; i++) an[i] = *(const bf16x8*)(sB + i * (16 * BKQ));
    #pragma unroll
    for (int j = 0; j < 4; j++) bm[j] = *(const bf16x8*)(sA + j * (16 * BKQ));
    if (t < NT_Q - 3) QSTAGE_A(t + 3);
    __builtin_amdgcn_s_barrier();
    __builtin_amdgcn_s_setprio(1);
    #pragma unroll
    for (int i = 0; i < 4; i++)
      #pragma unroll
      for (int j = 0; j < 4; j++)
        acc[i][j] = __builtin_amdgcn_mfma_f32_16x16x32_bf16(an[i], bm[j], acc[i][j], 0, 0, 0);
    __builtin_amdgcn_s_setprio(0);
    // ---- phase 2: read second half of A-frags, stage B(t+3), boundary wait, 16 MFMA
    #pragma unroll
    for (int j = 0; j < 4; j++) bm2[j] = *(const bf16x8*)(sA + (4 + j) * (16 * BKQ));
    if (t < NT_Q - 3) QSTAGE_B(t + 3);
    // boundary: ensure K-tile t+1 landed (counted, never 0 until drain), and our
    // own ds_reads of slot t&3 done before any wave can issue its overwriter.
    if (t < NT_Q - 3) {
      asm volatile("s_waitcnt vmcnt(8) lgkmcnt(0)" ::: "memory");
      __builtin_amdgcn_s_barrier();
    } else if (t == NT_Q - 3) {
      asm volatile("s_waitcnt vmcnt(4) lgkmcnt(0)" ::: "memory");
      __builtin_amdgcn_s_barrier();
    } else if (t == NT_Q - 2) {
      asm volatile("s_waitcnt vmcnt(0) lgkmcnt(0)" ::: "memory");
      __builtin_amdgcn_s_barrier();
    }
    __builtin_amdgcn_s_setprio(1);
    #pragma unroll
    for (int i = 0; i < 4; i++)
      #pragma unroll
      for (int j = 0; j < 4; j++)
        acc[i][4 + j] = __builtin_amdgcn_mfma_f32_16x16x32_bf16(an[i], bm2[j], acc[i][4 + j], 0, 0, 0);
    __builtin_amdgcn_s_setprio(0);
  }
#undef QSTAGE_A
#undef QSTAGE_B

  // epilogue: transposed C/D -> lane holds 4 consecutive n (channels), m = col.
  // BN=256 and each qkv third is 1024 = 4 block-cols, so `which` is block-uniform.
  const int which = n0 >> 10;  // 0=q,1=k,2=v
  unsigned short* dst = (which == 0) ? qh : (which == 1) ? kh : vh;
  #pragma unroll
  for (int i = 0; i < 4; i++) {
    const int n = n0 + wn + i * 16 + lq * 4;
    const int h = (n & 1023) >> 6, dd = n & 63;
    const float4 bi = *(const float4*)&bias[n];
    #pragma unroll
    for (int j = 0; j < 8; j++) {
      const int m = m0 + wm + j * 16 + lr;
      const int b = m >> 11, tg = m & 2047;
      float v0 = acc[i][j][0] + bi.x, v1 = acc[i][j][1] + bi.y;
      float v2 = acc[i][j][2] + bi.z, v3 = acc[i][j][3] + bi.w;
      if (which < 2) { v0 = featmap(v0); v1 = featmap(v1); v2 = featmap(v2); v3 = featmap(v3); }
      ushort4 o; o.x = f2bf(v0); o.y = f2bf(v1); o.z = f2bf(v2); o.w = f2bf(v3);
      *(ushort4*)&dst[(((size_t)(b * HH + h)) * TT + tg) * DD + dd] = o;
    }
  }
}

// ---------------- GEMM 2: out = y @ W_proj + b_proj (fp32 out) ----------------
__global__ __launch_bounds__(256) void gemm_proj_kernel(
    const unsigned short* __restrict__ A, const unsigned short* __restrict__ Bt,
    const float* __restrict__ bias, float* __restrict__ out) {
  GEMM_K_LOOP(A, Bt, CC)
  #pragma unroll
  for (int i = 0; i < 4; i++) {
    int n = n0 + wn + i * 16 + lq * 4;
    float4 bi = *(const float4*)&bias[n];
    #pragma unroll
    for (int j = 0; j < 4; j++) {
      int m = m0 + wm + j * 16 + lr;
      float4 o;
      o.x = acc[i][j][0] + bi.x; o.y = acc[i][j][1] + bi.y;
      o.z = acc[i][j][2] + bi.z; o.w = acc[i][j][3] + bi.w;
      *(float4*)&out[(size_t)m * CC + n] = o;
    }
  }
}

// ---------------- Phase A: per-chunk KV state (MFMA) ----------------
// grid: B*H*NCH blocks, 256 threads.
// KVx[blk][80][64] fp32, stored TRANSPOSED: KVx[j][i] = (K_c^T V_ext)[i][j],
// where V_ext = [V | ones | 0...] so col 64 is ksum. Rows 65..79 are zero.
__global__ __launch_bounds__(256) void chunk_state_kernel(
    const unsigned short* __restrict__ kh, const unsigned short* __restrict__ vh,
    float* __restrict__ KVx) {
  __shared__ __align__(16) unsigned short Kt[64 * VTST];   // K^T: Kt[i][t]
  __shared__ __align__(16) unsigned short Vt[80 * VTST];   // V^T + ones/zero rows
  int blk = blockIdx.x;
  int bh = blk / NCH, c = blk % NCH;
  int tid = threadIdx.x;
  const unsigned short* kp = kh + ((size_t)bh * TT + c * LCH) * DD;
  const unsigned short* vp = vh + ((size_t)bh * TT + c * LCH) * DD;
  {
    int t = tid & 127;
    for (int j8 = (tid >> 7) * 8; j8 < DD; j8 += 16) {
      union { uint4 u; unsigned short s[8]; } wk, wv;
      wk.u = *(const uint4*)&kp[(size_t)t * DD + j8];
      wv.u = *(const uint4*)&vp[(size_t)t * DD + j8];
      #pragma unroll
      for (int jj = 0; jj < 8; jj++) {
        Kt[(j8 + jj) * VTST + t] = wk.s[jj];
        Vt[(j8 + jj) * VTST + t] = wv.s[jj];
      }
    }
  }
  for (int e = tid; e < 16 * 128; e += 256) {
    int rr = e >> 7, n = e & 127;
    Vt[(64 + rr) * VTST + n] = (rr == 0) ? (unsigned short)0x3F80 : (unsigned short)0;
  }
  __syncthreads();
  int wave = tid >> 6, lane = tid & 63;
  int lr = lane & 15, lq = lane >> 4;
  int i0 = wave * 16;             // wave's 16-row band of K^T (i dimension)
  floatx4 acc[5] = {};
  #pragma unroll
  for (int kk = 0; kk < 4; kk++) {
    bf16x8 a = *(const bf16x8*)&Kt[(i0 + lr) * VTST + kk * 32 + lq * 8];
    #pragma unroll
    for (int jt = 0; jt < 5; jt++) {
      bf16x8 b = *(const bf16x8*)&Vt[(jt * 16 + lr) * VTST + kk * 32 + lq * 8];
      acc[jt] = __builtin_amdgcn_mfma_f32_16x16x32_bf16(a, b, acc[jt], 0, 0, 0);
    }
  }
  // C/D: col(j) = lane&15, row(i) = i0 + lq*4 + r; store transposed [j][i].
  float* o = KVx + (size_t)blk * 5120;
  #pragma unroll
  for (int jt = 0; jt < 5; jt++)
    *(float4*)&o[(jt * 16 + lr) * 64 + i0 + lq * 4] = *(float4*)&acc[jt];
}

// ---------------- Phase B: exclusive prefix over chunks -> bf16 SP_ext ----------
__global__ __launch_bounds__(256) void prefix_state_kernel(const float* __restrict__ KVx,
                                                           unsigned short* __restrict__ SPb) {
  int bh = blockIdx.x / 5, jb = blockIdx.x % 5;
  int e = jb * 1024 + threadIdx.x * 4;
  float run0 = 0.f, run1 = 0.f, run2 = 0.f, run3 = 0.f;
  for (int c = 0; c < NCH; c++) {
    size_t base = ((size_t)bh * NCH + c) * 5120 + e;
    float4 v = *(const float4*)&KVx[base];
    ushort4 o;
    o.x = f2bf(run0); o.y = f2bf(run1); o.z = f2bf(run2); o.w = f2bf(run3);
    *(ushort4*)&SPb[base] = o;
    run0 += v.x; run1 += v.y; run2 += v.z; run3 += v.w;
  }
}

// ---------------- Phase C: per-chunk attention output (MFMA, transposed) ----------
__global__ __launch_bounds__(256) void chunk_attn_kernel(
    const unsigned short* __restrict__ qh, const unsigned short* __restrict__ kh,
    const unsigned short* __restrict__ vh, const unsigned short* __restrict__ SPb,
    unsigned short* __restrict__ yb) {
  // region A: Qs[128][72] + Ks[128][72] = 18432 shorts, reused as P[128][136] = 17408
  // region B: Vt[80][136] = 10880 shorts
  __shared__ __align__(16) unsigned short lds[128 * QKST * 2 + 80 * VTST];  // 58624 B
  unsigned short* Qs = lds;                       // [128][QKST]
  unsigned short* Ks = lds + 128 * QKST;          // [128][QKST]
  unsigned short* P  = lds;                       // [128][PST] (after Qs/Ks dead)
  unsigned short* Vt = lds + 128 * QKST * 2;      // [80][VTST]

  int blk = blockIdx.x;
  int bh = blk / NCH, c = blk % NCH;
  int b = bh / HH, h = bh % HH;
  int tid = threadIdx.x;
  const unsigned short* qp = qh + ((size_t)bh * TT + c * LCH) * DD;
  const unsigned short* kp = kh + ((size_t)bh * TT + c * LCH) * DD;
  const unsigned short* vp = vh + ((size_t)bh * TT + c * LCH) * DD;

  // stage Q, K (row-major, padded stride)
  for (int e = tid; e < 1024; e += 256) {
    int row = e >> 3, k8 = (e & 7) * 8;
    *(uint4*)&Qs[row * QKST + k8] = *(const uint4*)&qp[(size_t)row * DD + k8];
    *(uint4*)&Ks[row * QKST + k8] = *(const uint4*)&kp[(size_t)row * DD + k8];
  }
  // stage V transposed: Vt[j][t] = V[t][j]
  {
    int t = tid & 127;
    for (int j8 = (tid >> 7) * 8; j8 < DD; j8 += 16) {
      union { uint4 u; unsigned short s[8]; } w;
      w.u = *(const uint4*)&vp[(size_t)t * DD + j8];
      #pragma unroll
      for (int jj = 0; jj < 8; jj++) Vt[(j8 + jj) * VTST + t] = w.s[jj];
    }
  }
  // ones row (j=64) and zero rows (65..79)
  for (int e = tid; e < 16 * 128; e += 256) {
    int rr = e >> 7, n = e & 127;
    Vt[(64 + rr) * VTST + n] = (rr == 0) ? (unsigned short)0x3F80 : (unsigned short)0;
  }
  __syncthreads();

  int wave = tid >> 6, lane = tid & 63;
  int lr = lane & 15, lq = lane >> 4;
  int mbase = wave * 32;

  // Q frags for this wave's two 16-row t-tiles (A-op for QK, B-op for QSP)
  bf16x8 aq[2][2];
  #pragma unroll
  for (int i = 0; i < 2; i++)
    #pragma unroll
    for (int kk = 0; kk < 2; kk++)
      aq[i][kk] = *(const bf16x8*)&Qs[(mbase + i * 16 + lr) * QKST + kk * 32 + lq * 8];

  // accT[jt][it]: D[j][t], rows j = jt*16 + lq*4 + r, cols t = mbase + it*16 + lr
  floatx4 accT[5][2] = {};
  // inter-chunk (transposed): accT += SP_ext^T-matmul: A = SPb rows [j][i], B = Q rows [t][i]
  const unsigned short* spb = SPb + (size_t)blk * (80 * 64);
  #pragma unroll
  for (int jt = 0; jt < 5; jt++)
    #pragma unroll
    for (int kk = 0; kk < 2; kk++) {
      bf16x8 asp = *(const bf16x8*)&spb[(jt * 16 + lr) * 64 + kk * 32 + lq * 8];
      accT[jt][0] = __builtin_amdgcn_mfma_f32_16x16x32_bf16(asp, aq[0][kk], accT[jt][0], 0, 0, 0);
      accT[jt][1] = __builtin_amdgcn_mfma_f32_16x16x32_bf16(asp, aq[1][kk], accT[jt][1], 0, 0, 0);
    }
  // intra-chunk scores: S = Q @ K^T (row=t(q), col=t'(k))
  floatx4 sacc[2][8] = {};
  #pragma unroll
  for (int nt = 0; nt < 8; nt++)
    #pragma unroll
    for (int kk = 0; kk < 2; kk++) {
      bf16x8 bk = *(const bf16x8*)&Ks[(nt * 16 + lr) * QKST + kk * 32 + lq * 8];
      sacc[0][nt] = __builtin_amdgcn_mfma_f32_16x16x32_bf16(aq[0][kk], bk, sacc[0][nt], 0, 0, 0);
      sacc[1][nt] = __builtin_amdgcn_mfma_f32_16x16x32_bf16(aq[1][kk], bk, sacc[1][nt], 0, 0, 0);
    }
  __syncthreads();  // everyone done reading Qs/Ks before P overwrites them

  // causal mask + bf16 round, C-layout -> LDS P[t][t']
  #pragma unroll
  for (int i = 0; i < 2; i++)
    #pragma unroll
    for (int nt = 0; nt < 8; nt++) {
      int col = nt * 16 + lr;
      #pragma unroll
      for (int r = 0; r < 4; r++) {
        int m = mbase + i * 16 + lq * 4 + r;
        float v = (col <= m) ? sacc[i][nt][r] : 0.f;
        P[m * PST + col] = f2bf(v);
      }
    }
  __syncthreads();

  // accT += (P @ V_ext)^T: A = Vt rows [j][t'], B = P rows [t][t']
  #pragma unroll
  for (int kk4 = 0; kk4 < 4; kk4++) {
    bf16x8 bp0 = *(const bf16x8*)&P[(mbase + lr) * PST + kk4 * 32 + lq * 8];
    bf16x8 bp1 = *(const bf16x8*)&P[(mbase + 16 + lr) * PST + kk4 * 32 + lq * 8];
    #pragma unroll
    for (int jt = 0; jt < 5; jt++) {
      bf16x8 av = *(const bf16x8*)&Vt[(jt * 16 + lr) * VTST + kk4 * 32 + lq * 8];
      accT[jt][0] = __builtin_amdgcn_mfma_f32_16x16x32_bf16(av, bp0, accT[jt][0], 0, 0, 0);
      accT[jt][1] = __builtin_amdgcn_mfma_f32_16x16x32_bf16(av, bp1, accT[jt][1], 0, 0, 0);
    }
  }

  // epilogue: den = row 64 = accT[4][it] reg0 on lanes lq=0, col=t=lane&15.
  #pragma unroll
  for (int it = 0; it < 2; it++) {
    float den = __shfl(accT[4][it][0], lr, 64);
    float inv = 1.f / (den + EPSF);
    int tg = c * LCH + mbase + it * 16 + lr;
    size_t base = ((size_t)b * TT + tg) * CC + h * DD;
    #pragma unroll
    for (int jt = 0; jt < 4; jt++) {
      ushort4 o;
      o.x = f2bf(accT[jt][it][0] * inv);
      o.y = f2bf(accT[jt][it][1] * inv);
      o.z = f2bf(accT[jt][it][2] * inv);
      o.w = f2bf(accT[jt][it][3] * inv);
      *(ushort4*)&yb[base + jt * 16 + lq * 4] = o;
    }
  }
}

// ---------------- host launch ----------------
extern "C" void kernel_launch(void* const* d_in, const int* in_sizes, int n_in,
                              void* d_out, int out_size, void* d_ws, size_t ws_size,
                              hipStream_t stream) {
  const float* x      = (const float*)d_in[0];
  const float* W_attn = (const float*)d_in[1];
  const float* b_attn = (const float*)d_in[2];
  const float* W_proj = (const float*)d_in[3];
  const float* b_proj = (const float*)d_in[4];
  float* out = (float*)d_out;

  char* ws = (char*)d_ws;
  size_t off = 0;
  auto alloc = [&](size_t bytes) -> char* {
    char* p = ws + off;
    off += (bytes + 255) & ~(size_t)255;
    return p;
  };
  unsigned short* xb  = (unsigned short*)alloc((size_t)MM * CC * 2);   // reused as yb
  unsigned short* WaT = (unsigned short*)alloc((size_t)NQKV * CC * 2);
  unsigned short* WpT = (unsigned short*)alloc((size_t)CC * CC * 2);
  unsigned short* qh  = (unsigned short*)alloc((size_t)MM * CC * 2);
  unsigned short* kh  = (unsigned short*)alloc((size_t)MM * CC * 2);
  unsigned short* vh  = (unsigned short*)alloc((size_t)MM * CC * 2);
  float* KVx = (float*)alloc((size_t)BB * HH * NCH * 80 * 64 * 4);
  unsigned short* SPb = (unsigned short*)alloc((size_t)BB * HH * NCH * 80 * 64 * 2);
  unsigned short* yb = xb;  // xb dead after gemm_qkv

  static bool s_attr_done = false;
  if (!s_attr_done) {
    (void)hipFuncSetAttribute((const void*)gemm_qkv_kernel,
                              hipFuncAttributeMaxDynamicSharedMemorySize, 131072);
    s_attr_done = true;
  }

  prep_kernel<<<12288, 256, 0, stream>>>(x, xb, W_attn, WaT, W_proj, WpT);
  gemm_qkv_kernel<<<dim3(NQKV / 256, MM / 256), 512, 131072, stream>>>(xb, WaT, b_attn, qh, kh, vh);
  chunk_state_kernel<<<BB * HH * NCH, 256, 0, stream>>>(kh, vh, KVx);
  prefix_state_kernel<<<BB * HH * 5, 256, 0, stream>>>(KVx, SPb);
  chunk_attn_kernel<<<BB * HH * NCH, 256, 0, stream>>>(qh, kh, vh, SPb, yb);
  gemm_proj_kernel<<<dim3(CC / 128, MM / 128), 256, 0, stream>>>(yb, WpT, b_proj, out);
}

// Round 2
// 235.783 us; speedup vs baseline: 1.0042x; 1.0042x over previous
//
#include <hip/hip_runtime.h>
#include <math.h>

// Problem constants (reference: B=4, T=2048, C=1024, H=16, d=64)
#define BB   4
#define TT   2048
#define CC   1024
#define HH   16
#define DD   64
#define MM   (BB*TT)     // 8192 rows
#define NQKV (3*CC)      // 3072
#define LCH  128         // attention chunk length
#define NCH  (TT/LCH)    // 16 chunks per (b,h)
#define EPSF 1e-6f

// LDS strides (in shorts) for attention kernels — padded to break bank aliasing
#define QKST 72          // Q/K tile row stride
#define PST  136         // P tile row stride
#define VTST 136         // V-transposed tile row stride

typedef __bf16 bf16x8 __attribute__((ext_vector_type(8)));
typedef float  floatx4 __attribute__((ext_vector_type(4)));

__device__ __forceinline__ unsigned short f2bf(float f) {
  union { float f; unsigned int u; } v; v.f = f;
  unsigned int r = v.u + 0x7fffu + ((v.u >> 16) & 1u); // RNE
  return (unsigned short)(r >> 16);
}
__device__ __forceinline__ float bf2f(unsigned short s) {
  union { unsigned int u; float f; } v; v.u = ((unsigned int)s) << 16;
  return v.f;
}
__device__ __forceinline__ float featmap(float v) {
  // elu(v)+1
  return v > 0.f ? v + 1.f : __expf(v);
}
// async global->LDS, 16B per lane; LDS dest = wave-uniform base + lane*16
__device__ __forceinline__ void gld_lds_b128(const unsigned short* g, unsigned short* l) {
  __builtin_amdgcn_global_load_lds(
      (const __attribute__((address_space(1))) unsigned int*)g,
      (__attribute__((address_space(3))) unsigned int*)l, 16, 0, 0);
}

// ---------------- prep: x->bf16 + both weight transposes, one kernel ----------------
__device__ __forceinline__ void transpose_cvt_body(const float* __restrict__ W,
                                                   unsigned short* __restrict__ out,
                                                   int R, int Cc, int bx32, int by32, int tid) {
  __shared__ float tile[32][33];
  int tx = tid & 31, ty = tid >> 5;  // 32 x 8
  int bx = bx32 * 32, by = by32 * 32;
  #pragma unroll
  for (int i = ty; i < 32; i += 8)
    tile[i][tx] = W[(size_t)(by + i) * Cc + bx + tx];
  __syncthreads();
  #pragma unroll
  for (int i = ty; i < 32; i += 8)
    out[(size_t)(bx + i) * R + by + tx] = f2bf(tile[tx][i]);
}

// grid: [0,8192) cvt_x | [8192,11264) W_attn transpose | [11264,12288) W_proj transpose
__global__ __launch_bounds__(256) void prep_kernel(
    const float* __restrict__ x, unsigned short* __restrict__ xb,
    const float* __restrict__ Wa, unsigned short* __restrict__ WaT,
    const float* __restrict__ Wp, unsigned short* __restrict__ WpT) {
  int blk = blockIdx.x, tid = threadIdx.x;
  if (blk < 8192) {
    int i = (blk * 256 + tid) * 4;
    float4 f = *(const float4*)(x + i);
    ushort4 o;
    o.x = f2bf(f.x); o.y = f2bf(f.y); o.z = f2bf(f.z); o.w = f2bf(f.w);
    *(ushort4*)(xb + i) = o;
  } else if (blk < 8192 + 3072) {
    int t = blk - 8192;                       // 96 x 32
    transpose_cvt_body(Wa, WaT, CC, NQKV, t % 96, t / 96, tid);
  } else {
    int t = blk - 11264;                      // 32 x 32
    transpose_cvt_body(Wp, WpT, CC, CC, t % 32, t / 32, tid);
  }
}

// ============== MFMA GEMM core: 128x128 tile, BK=64 (R6 known-good shape) ==========
// Used by gemm_proj (N=1024). Unchanged from the verified baseline.
#define GEMM_K_LOOP(A_, Bt_, K_)                                                 \
  __shared__ __align__(16) unsigned short As[128 * 64];                          \
  __shared__ __align__(16) unsigned short Bs[128 * 64];                          \
  int tid = threadIdx.x;                                                         \
  int wave = tid >> 6, lane = tid & 63;                                          \
  int lr = lane & 15, lq = lane >> 4;                                            \
  int m0 = blockIdx.y * 128, n0 = blockIdx.x * 128;                              \
  int wm = (wave >> 1) * 64, wn = (wave & 1) * 64;                               \
  int lrow = lane >> 3;                 /* 0..7: row within 8-row chunk */       \
  int lk = (lane & 7) ^ lrow;           /* swizzled source k-chunk */            \
  int rbase = wave * 32;                                                         \
  const unsigned short* gA = A_ + (size_t)(m0 + rbase + lrow) * K_ + lk * 8;     \
  const unsigned short* gB = Bt_ + (size_t)(n0 + rbase + lrow) * K_ + lk * 8;    \
  unsigned short* lA = As + rbase * 64;                                          \
  unsigned short* lB = Bs + rbase * 64;                                          \
  floatx4 acc[4][4] = {};                                                        \
  for (int k0 = 0; k0 < K_; k0 += 64) {                                          \
    __syncthreads(); /* prior frag reads done before overwrite */                \
    _Pragma("unroll")                                                            \
    for (int g = 0; g < 4; g++) {                                                \
      gld_lds_b128(gA + k0 + (size_t)g * 8 * K_, lA + g * 512);                  \
      gld_lds_b128(gB + k0 + (size_t)g * 8 * K_, lB + g * 512);                  \
    }                                                                            \
    __syncthreads(); /* staged data visible */                                   \
    _Pragma("unroll")                                                            \
    for (int kk = 0; kk < 2; kk++) {                                             \
      bf16x8 an[4], bm[4];                                                       \
      _Pragma("unroll")                                                          \
      for (int i = 0; i < 4; i++)                                                \
        an[i] = *(const bf16x8*)&Bs[(wn + i * 16 + lr) * 64 + ((((kk << 2) + lq) ^ (lr & 7)) << 3)]; \
      _Pragma("unroll")                                                          \
      for (int j = 0; j < 4; j++)                                                \
        bm[j] = *(const bf16x8*)&As[(wm + j * 16 + lr) * 64 + ((((kk << 2) + lq) ^ (lr & 7)) << 3)]; \
      _Pragma("unroll")                                                          \
      for (int i = 0; i < 4; i++)                                                \
        _Pragma("unroll")                                                        \
        for (int j = 0; j < 4; j++)                                              \
          acc[i][j] = __builtin_amdgcn_mfma_f32_16x16x32_bf16(an[i], bm[j], acc[i][j], 0, 0, 0); \
    }                                                                            \
  }

// ---------------- GEMM 1: qkv = x @ W_attn + b, split + feature map ----------------
// R10: BM=256 x BN=192, BK=32, 512 thr / 8 waves (2M x 4N groups), 4-slot LDS ring
// (112 KiB dynamic), m201-style phase schedule: per K-tile 2 phases of
// {ds_read frags | issue gld_lds stage -> s_barrier -> lgkmcnt(0) -> setprio(1) +
// 12 MFMA + setprio(0) -> s_barrier}, counted vmcnt(6) boundary once per K-tile
// (drain 6->3->0 at the tail). Grid = 16x32 = 512 blocks = EXACTLY 2.0 rounds at
// 1 block/CU -> no occupancy tail (R9's 1.5-round tail cost 25%).
// B (192 rows) stages asymmetrically: waves 0-3 issue 4 glds/tile, waves 4-7 issue 3;
// uniform vmcnt(6) = 2-tile depth for waves 4-7, slight over-wait for 0-3 (safe).
// K summation order identical to baseline -> bitwise-identical results.
#define BKQ   32
#define ASLT  (256 * BKQ)   // 8192 shorts / slot
#define BSLT  (192 * BKQ)   // 6144 shorts / slot
#define NT_Q  (CC / BKQ)    // 32 K-tiles

__global__ __launch_bounds__(512, 2) void gemm_qkv_kernel(
    const unsigned short* __restrict__ A, const unsigned short* __restrict__ Bt,
    const float* __restrict__ bias,
    unsigned short* __restrict__ qh, unsigned short* __restrict__ kh,
    unsigned short* __restrict__ vh) {
  extern __shared__ __align__(16) unsigned short lds[];
  unsigned short* Ar = lds;                 // [4][256][32]
  unsigned short* Br = lds + 4 * ASLT;      // [4][192][32]

  const int tid = threadIdx.x;
  const int wave = tid >> 6, lane = tid & 63;
  const int lr = lane & 15, lq = lane >> 4;
  const int m0 = blockIdx.y * 256, n0 = blockIdx.x * 192;
  const int wm = (wave >> 2) * 128, wn = (wave & 3) * 48;

  // staging map: wave w covers rows [w*16, w*16+16) (+128 for the g1 load);
  // lane l -> row w*16 + (l>>2), LDS chunk l&3 (linear dest, 4 chunks x 8 shorts).
  // Global source chunk pre-swizzled: cs = (l&3) ^ ((row>>1)&3) = (l&3) ^ ((l>>3)&3).
  const int srow = wave * 16 + (lane >> 2);
  const int cs = (lane & 3) ^ ((lane >> 3) & 3);
  const unsigned short* gA0 = A  + (size_t)(m0 + srow) * CC + cs * 8;
  const unsigned short* gB0 = Bt + (size_t)(n0 + srow) * CC + cs * 8;
  unsigned short* const stA = Ar + wave * 512;   // wave-uniform LDS dest base
  unsigned short* const stB = Br + wave * 512;
  const bool bhi = (wave < 4);                   // waves 0-3 stage B rows 128..191

  // reader: global chunk lq at row r lives in LDS chunk lq ^ ((r>>1)&3);
  // r = frag_base + lr with frag_base % 16 == 0 -> (r>>1)&3 == (lr>>1)&3.
  const int chunk = lq ^ ((lr >> 1) & 3);
  const int roA = (wm + lr) * BKQ + chunk * 8;
  const int roB = (wn + lr) * BKQ + chunk * 8;

  floatx4 acc[3][8] = {};   // [n-frag][m-frag], transposed-C convention

#define QSTAGE_A(tt) do {                                      \
    const unsigned short* g_ = gA0 + (tt) * BKQ;               \
    unsigned short* d_ = stA + ((tt) & 3) * ASLT;              \
    gld_lds_b128(g_, d_);                                      \
    gld_lds_b128(g_ + (size_t)128 * CC, d_ + 4096);            \
  } while (0)
#define QSTAGE_B(tt) do {                                      \
    const unsigned short* g_ = gB0 + (tt) * BKQ;               \
    unsigned short* d_ = stB + ((tt) & 3) * BSLT;              \
    gld_lds_b128(g_, d_);                                      \
    if (bhi) gld_lds_b128(g_ + (size_t)128 * CC, d_ + 4096);   \
  } while (0)

  // prologue: stage K-tiles 0,1,2; wait tile 0 (keep tiles 1,2 in flight)
  QSTAGE_A(0); QSTAGE_B(0);
  QSTAGE_A(1); QSTAGE_B(1);
  QSTAGE_A(2); QSTAGE_B(2);
  asm volatile("s_waitcnt vmcnt(6)" ::: "memory");
  __builtin_amdgcn_s_barrier();

  #pragma unroll 4
  for (int t = 0; t < NT_Q; ++t) {
    const unsigned short* sA = Ar + (t & 3) * ASLT + roA;
    const unsigned short* sB = Br + (t & 3) * BSLT + roB;
    bf16x8 an[3], bm[4], bm2[4];
    // ---- phase 1: n-frags + first 4 m-frags; stage A(t+3); 12 MFMA
    #pragma unroll
    for (int i = 0; i < 3; i++) an[i] = *(const bf16x8*)(sB + i * (16 * BKQ));
    #pragma unroll
    for (int j = 0; j < 4; j++) bm[j] = *(const bf16x8*)(sA + j * (16 * BKQ));
    if (t < NT_Q - 3) QSTAGE_A(t + 3);
    __builtin_amdgcn_s_barrier();
    asm volatile("s_waitcnt lgkmcnt(0)" ::: "memory");
    __builtin_amdgcn_s_setprio(1);
    #pragma unroll
    for (int i = 0; i < 3; i++)
      #pragma unroll
      for (int j = 0; j < 4; j++)
        acc[i][j] = __builtin_amdgcn_mfma_f32_16x16x32_bf16(an[i], bm[j], acc[i][j], 0, 0, 0);
    __builtin_amdgcn_s_setprio(0);
    __builtin_amdgcn_s_barrier();
    // ---- phase 2: last 4 m-frags; stage B(t+3); 12 MFMA; K-tile boundary vmcnt
    #pragma unroll
    for (int j = 0; j < 4; j++) bm2[j] = *(const bf16x8*)(sA + (4 + j) * (16 * BKQ));
    if (t < NT_Q - 3) QSTAGE_B(t + 3);
    __builtin_amdgcn_s_barrier();
    asm volatile("s_waitcnt lgkmcnt(0)" ::: "memory");
    __builtin_amdgcn_s_setprio(1);
    #pragma unroll
    for (int i = 0; i < 3; i++)
      #pragma unroll
      for (int j = 0; j < 4; j++)
        acc[i][4 + j] = __builtin_amdgcn_mfma_f32_16x16x32_bf16(an[i], bm2[j], acc[i][4 + j], 0, 0, 0);
    __builtin_amdgcn_s_setprio(0);
    // boundary: next tile's data must be resident; counted (never 0 until drain)
    if (t < NT_Q - 3)        asm volatile("s_waitcnt vmcnt(6)" ::: "memory");
    else if (t == NT_Q - 3)  asm volatile("s_waitcnt vmcnt(3)" ::: "memory");
    else if (t == NT_Q - 2)  asm volatile("s_waitcnt vmcnt(0)" ::: "memory");
    __builtin_amdgcn_s_barrier();
  }
#undef QSTAGE_A
#undef QSTAGE_B

  // epilogue: transposed C/D -> lane holds 4 consecutive n (channels), m = col.
  // BN=192 crosses q/k/v 1024-boundaries -> select dst per i-frag (static unroll).
  // j outer / i inner so both 32B halves of an output line are written adjacently.
  unsigned short* dstv[3];
  size_t qoff[3];
  float4 bi[3];
  bool feat[3];
  #pragma unroll
  for (int i = 0; i < 3; i++) {
    const int n = n0 + wn + i * 16 + lq * 4;
    dstv[i] = (n < 1024) ? qh : (n < 2048) ? kh : vh;
    feat[i] = (n < 2048);
    const int h = (n & 1023) >> 6, dd = n & 63;
    qoff[i] = (size_t)h * (TT * DD) + dd;
    bi[i] = *(const float4*)&bias[n];
  }
  #pragma unroll
  for (int j = 0; j < 8; j++) {
    const int m = m0 + wm + j * 16 + lr;
    const int b = m >> 11, tg = m & 2047;
    const size_t pj = (size_t)b * (HH * TT * DD) + (size_t)tg * DD;
    #pragma unroll
    for (int i = 0; i < 3; i++) {
      float v0 = acc[i][j][0] + bi[i].x, v1 = acc[i][j][1] + bi[i].y;
      float v2 = acc[i][j][2] + bi[i].z, v3 = acc[i][j][3] + bi[i].w;
      if (feat[i]) { v0 = featmap(v0); v1 = featmap(v1); v2 = featmap(v2); v3 = featmap(v3); }
      ushort4 o; o.x = f2bf(v0); o.y = f2bf(v1); o.z = f2bf(v2); o.w = f2bf(v3);
      *(ushort4*)&dstv[i][pj + qoff[i]] = o;
    }
  }
}

// ---------------- GEMM 2: out = y @ W_proj + b_proj (fp32 out) ----------------
__global__ __launch_bounds__(256) void gemm_proj_kernel(
    const unsigned short* __restrict__ A, const unsigned short* __restrict__ Bt,
    const float* __restrict__ bias, float* __restrict__ out) {
  GEMM_K_LOOP(A, Bt, CC)
  #pragma unroll
  for (int i = 0; i < 4; i++) {
    int n = n0 + wn + i * 16 + lq * 4;
    float4 bi = *(const float4*)&bias[n];
    #pragma unroll
    for (int j = 0; j < 4; j++) {
      int m = m0 + wm + j * 16 + lr;
      float4 o;
      o.x = acc[i][j][0] + bi.x; o.y = acc[i][j][1] + bi.y;
      o.z = acc[i][j][2] + bi.z; o.w = acc[i][j][3] + bi.w;
      *(float4*)&out[(size_t)m * CC + n] = o;
    }
  }
}

// ---------------- Phase A: per-chunk KV state (MFMA) ----------------
// grid: B*H*NCH blocks, 256 threads.
// KVx[blk][80][64] fp32, stored TRANSPOSED: KVx[j][i] = (K_c^T V_ext)[i][j],
// where V_ext = [V | ones | 0...] so col 64 is ksum. Rows 65..79 are zero.
__global__ __launch_bounds__(256) void chunk_state_kernel(
    const unsigned short* __restrict__ kh, const unsigned short* __restrict__ vh,
    float* __restrict__ KVx) {
  __shared__ __align__(16) unsigned short Kt[64 * VTST];   // K^T: Kt[i][t]
  __shared__ __align__(16) unsigned short Vt[80 * VTST];   // V^T + ones/zero rows
  int blk = blockIdx.x;
  int bh = blk / NCH, c = blk % NCH;
  int tid = threadIdx.x;
  const unsigned short* kp = kh + ((size_t)bh * TT + c * LCH) * DD;
  const unsigned short* vp = vh + ((size_t)bh * TT + c * LCH) * DD;
  {
    int t = tid & 127;
    for (int j8 = (tid >> 7) * 8; j8 < DD; j8 += 16) {
      union { uint4 u; unsigned short s[8]; } wk, wv;
      wk.u = *(const uint4*)&kp[(size_t)t * DD + j8];
      wv.u = *(const uint4*)&vp[(size_t)t * DD + j8];
      #pragma unroll
      for (int jj = 0; jj < 8; jj++) {
        Kt[(j8 + jj) * VTST + t] = wk.s[jj];
        Vt[(j8 + jj) * VTST + t] = wv.s[jj];
      }
    }
  }
  for (int e = tid; e < 16 * 128; e += 256) {
    int rr = e >> 7, n = e & 127;
    Vt[(64 + rr) * VTST + n] = (rr == 0) ? (unsigned short)0x3F80 : (unsigned short)0;
  }
  __syncthreads();
  int wave = tid >> 6, lane = tid & 63;
  int lr = lane & 15, lq = lane >> 4;
  int i0 = wave * 16;             // wave's 16-row band of K^T (i dimension)
  floatx4 acc[5] = {};
  #pragma unroll
  for (int kk = 0; kk < 4; kk++) {
    bf16x8 a = *(const bf16x8*)&Kt[(i0 + lr) * VTST + kk * 32 + lq * 8];
    #pragma unroll
    for (int jt = 0; jt < 5; jt++) {
      bf16x8 b = *(const bf16x8*)&Vt[(jt * 16 + lr) * VTST + kk * 32 + lq * 8];
      acc[jt] = __builtin_amdgcn_mfma_f32_16x16x32_bf16(a, b, acc[jt], 0, 0, 0);
    }
  }
  // C/D: col(j) = lane&15, row(i) = i0 + lq*4 + r; store transposed [j][i].
  float* o = KVx + (size_t)blk * 5120;
  #pragma unroll
  for (int jt = 0; jt < 5; jt++)
    *(float4*)&o[(jt * 16 + lr) * 64 + i0 + lq * 4] = *(float4*)&acc[jt];
}

// ---------------- Phase B: exclusive prefix over chunks -> bf16 SP_ext ----------
__global__ __launch_bounds__(256) void prefix_state_kernel(const float* __restrict__ KVx,
                                                           unsigned short* __restrict__ SPb) {
  int bh = blockIdx.x / 5, jb = blockIdx.x % 5;
  int e = jb * 1024 + threadIdx.x * 4;
  float run0 = 0.f, run1 = 0.f, run2 = 0.f, run3 = 0.f;
  for (int c = 0; c < NCH; c++) {
    size_t base = ((size_t)bh * NCH + c) * 5120 + e;
    float4 v = *(const float4*)&KVx[base];
    ushort4 o;
    o.x = f2bf(run0); o.y = f2bf(run1); o.z = f2bf(run2); o.w = f2bf(run3);
    *(ushort4*)&SPb[base] = o;
    run0 += v.x; run1 += v.y; run2 += v.z; run3 += v.w;
  }
}

// ---------------- Phase C: per-chunk attention output (MFMA, transposed) ----------
// R10: + s_setprio around the three MFMA clusters (2 independent blocks/CU at
// different phases -> scheduler has something to arbitrate; m191 regime).
__global__ __launch_bounds__(256) void chunk_attn_kernel(
    const unsigned short* __restrict__ qh, const unsigned short* __restrict__ kh,
    const unsigned short* __restrict__ vh, const unsigned short* __restrict__ SPb,
    unsigned short* __restrict__ yb) {
  // region A: Qs[128][72] + Ks[128][72] = 18432 shorts, reused as P[128][136] = 17408
  // region B: Vt[80][136] = 10880 shorts
  __shared__ __align__(16) unsigned short lds[128 * QKST * 2 + 80 * VTST];  // 58624 B
  unsigned short* Qs = lds;                       // [128][QKST]
  unsigned short* Ks = lds + 128 * QKST;          // [128][QKST]
  unsigned short* P  = lds;                       // [128][PST] (after Qs/Ks dead)
  unsigned short* Vt = lds + 128 * QKST * 2;      // [80][VTST]

  int blk = blockIdx.x;
  int bh = blk / NCH, c = blk % NCH;
  int b = bh / HH, h = bh % HH;
  int tid = threadIdx.x;
  const unsigned short* qp = qh + ((size_t)bh * TT + c * LCH) * DD;
  const unsigned short* kp = kh + ((size_t)bh * TT + c * LCH) * DD;
  const unsigned short* vp = vh + ((size_t)bh * TT + c * LCH) * DD;

  // stage Q, K (row-major, padded stride)
  for (int e = tid; e < 1024; e += 256) {
    int row = e >> 3, k8 = (e & 7) * 8;
    *(uint4*)&Qs[row * QKST + k8] = *(const uint4*)&qp[(size_t)row * DD + k8];
    *(uint4*)&Ks[row * QKST + k8] = *(const uint4*)&kp[(size_t)row * DD + k8];
  }
  // stage V transposed: Vt[j][t] = V[t][j]
  {
    int t = tid & 127;
    for (int j8 = (tid >> 7) * 8; j8 < DD; j8 += 16) {
      union { uint4 u; unsigned short s[8]; } w;
      w.u = *(const uint4*)&vp[(size_t)t * DD + j8];
      #pragma unroll
      for (int jj = 0; jj < 8; jj++) Vt[(j8 + jj) * VTST + t] = w.s[jj];
    }
  }
  // ones row (j=64) and zero rows (65..79)
  for (int e = tid; e < 16 * 128; e += 256) {
    int rr = e >> 7, n = e & 127;
    Vt[(64 + rr) * VTST + n] = (rr == 0) ? (unsigned short)0x3F80 : (unsigned short)0;
  }
  __syncthreads();

  int wave = tid >> 6, lane = tid & 63;
  int lr = lane & 15, lq = lane >> 4;
  int mbase = wave * 32;

  // Q frags for this wave's two 16-row t-tiles (A-op for QK, B-op for QSP)
  bf16x8 aq[2][2];
  #pragma unroll
  for (int i = 0; i < 2; i++)
    #pragma unroll
    for (int kk = 0; kk < 2; kk++)
      aq[i][kk] = *(const bf16x8*)&Qs[(mbase + i * 16 + lr) * QKST + kk * 32 + lq * 8];

  // accT[jt][it]: D[j][t], rows j = jt*16 + lq*4 + r, cols t = mbase + it*16 + lr
  floatx4 accT[5][2] = {};
  // inter-chunk (transposed): accT += SP_ext^T-matmul: A = SPb rows [j][i], B = Q rows [t][i]
  const unsigned short* spb = SPb + (size_t)blk * (80 * 64);
  __builtin_amdgcn_s_setprio(1);
  #pragma unroll
  for (int jt = 0; jt < 5; jt++)
    #pragma unroll
    for (int kk = 0; kk < 2; kk++) {
      bf16x8 asp = *(const bf16x8*)&spb[(jt * 16 + lr) * 64 + kk * 32 + lq * 8];
      accT[jt][0] = __builtin_amdgcn_mfma_f32_16x16x32_bf16(asp, aq[0][kk], accT[jt][0], 0, 0, 0);
      accT[jt][1] = __builtin_amdgcn_mfma_f32_16x16x32_bf16(asp, aq[1][kk], accT[jt][1], 0, 0, 0);
    }
  __builtin_amdgcn_s_setprio(0);
  // intra-chunk scores: S = Q @ K^T (row=t(q), col=t'(k))
  floatx4 sacc[2][8] = {};
  __builtin_amdgcn_s_setprio(1);
  #pragma unroll
  for (int nt = 0; nt < 8; nt++)
    #pragma unroll
    for (int kk = 0; kk < 2; kk++) {
      bf16x8 bk = *(const bf16x8*)&Ks[(nt * 16 + lr) * QKST + kk * 32 + lq * 8];
      sacc[0][nt] = __builtin_amdgcn_mfma_f32_16x16x32_bf16(aq[0][kk], bk, sacc[0][nt], 0, 0, 0);
      sacc[1][nt] = __builtin_amdgcn_mfma_f32_16x16x32_bf16(aq[1][kk], bk, sacc[1][nt], 0, 0, 0);
    }
  __builtin_amdgcn_s_setprio(0);
  __syncthreads();  // everyone done reading Qs/Ks before P overwrites them

  // causal mask + bf16 round, C-layout -> LDS P[t][t']
  #pragma unroll
  for (int i = 0; i < 2; i++)
    #pragma unroll
    for (int nt = 0; nt < 8; nt++) {
      int col = nt * 16 + lr;
      #pragma unroll
      for (int r = 0; r < 4; r++) {
        int m = mbase + i * 16 + lq * 4 + r;
        float v = (col <= m) ? sacc[i][nt][r] : 0.f;
        P[m * PST + col] = f2bf(v);
      }
    }
  __syncthreads();

  // accT += (P @ V_ext)^T: A = Vt rows [j][t'], B = P rows [t][t']
  #pragma unroll
  for (int kk4 = 0; kk4 < 4; kk4++) {
    bf16x8 bp0 = *(const bf16x8*)&P[(mbase + lr) * PST + kk4 * 32 + lq * 8];
    bf16x8 bp1 = *(const bf16x8*)&P[(mbase + 16 + lr) * PST + kk4 * 32 + lq * 8];
    __builtin_amdgcn_s_setprio(1);
    #pragma unroll
    for (int jt = 0; jt < 5; jt++) {
      bf16x8 av = *(const bf16x8*)&Vt[(jt * 16 + lr) * VTST + kk4 * 32 + lq * 8];
      accT[jt][0] = __builtin_amdgcn_mfma_f32_16x16x32_bf16(av, bp0, accT[jt][0], 0, 0, 0);
      accT[jt][1] = __builtin_amdgcn_mfma_f32_16x16x32_bf16(av, bp1, accT[jt][1], 0, 0, 0);
    }
    __builtin_amdgcn_s_setprio(0);
  }

  // epilogue: den = row 64 = accT[4][it] reg0 on lanes lq=0, col=t=lane&15.
  #pragma unroll
  for (int it = 0; it < 2; it++) {
    float den = __shfl(accT[4][it][0], lr, 64);
    float inv = 1.f / (den + EPSF);
    int tg = c * LCH + mbase + it * 16 + lr;
    size_t base = ((size_t)b * TT + tg) * CC + h * DD;
    #pragma unroll
    for (int jt = 0; jt < 4; jt++) {
      ushort4 o;
      o.x = f2bf(accT[jt][it][0] * inv);
      o.y = f2bf(accT[jt][it][1] * inv);
      o.z = f2bf(accT[jt][it][2] * inv);
      o.w = f2bf(accT[jt][it][3] * inv);
      *(ushort4*)&yb[base + jt * 16 + lq * 4] = o;
    }
  }
}

// ---------------- host launch ----------------
extern "C" void kernel_launch(void* const* d_in, const int* in_sizes, int n_in,
                              void* d_out, int out_size, void* d_ws, size_t ws_size,
                              hipStream_t stream) {
  const float* x      = (const float*)d_in[0];
  const float* W_attn = (const float*)d_in[1];
  const float* b_attn = (const float*)d_in[2];
  const float* W_proj = (const float*)d_in[3];
  const float* b_proj = (const float*)d_in[4];
  float* out = (float*)d_out;

  char* ws = (char*)d_ws;
  size_t off = 0;
  auto alloc = [&](size_t bytes) -> char* {
    char* p = ws + off;
    off += (bytes + 255) & ~(size_t)255;
    return p;
  };
  unsigned short* xb  = (unsigned short*)alloc((size_t)MM * CC * 2);   // reused as yb
  unsigned short* WaT = (unsigned short*)alloc((size_t)NQKV * CC * 2);
  unsigned short* WpT = (unsigned short*)alloc((size_t)CC * CC * 2);
  unsigned short* qh  = (unsigned short*)alloc((size_t)MM * CC * 2);
  unsigned short* kh  = (unsigned short*)alloc((size_t)MM * CC * 2);
  unsigned short* vh  = (unsigned short*)alloc((size_t)MM * CC * 2);
  float* KVx = (float*)alloc((size_t)BB * HH * NCH * 80 * 64 * 4);
  unsigned short* SPb = (unsigned short*)alloc((size_t)BB * HH * NCH * 80 * 64 * 2);
  unsigned short* yb = xb;  // xb dead after gemm_qkv

  static bool s_attr_done = false;
  if (!s_attr_done) {
    (void)hipFuncSetAttribute((const void*)gemm_qkv_kernel,
                              hipFuncAttributeMaxDynamicSharedMemorySize, 114688);
    s_attr_done = true;
  }

  prep_kernel<<<12288, 256, 0, stream>>>(x, xb, W_attn, WaT, W_proj, WpT);
  gemm_qkv_kernel<<<dim3(NQKV / 192, MM / 256), 512, 114688, stream>>>(xb, WaT, b_attn, qh, kh, vh);
  chunk_state_kernel<<<BB * HH * NCH, 256, 0, stream>>>(kh, vh, KVx);
  prefix_state_kernel<<<BB * HH * 5, 256, 0, stream>>>(KVx, SPb);
  chunk_attn_kernel<<<BB * HH * NCH, 256, 0, stream>>>(qh, kh, vh, SPb, yb);
  gemm_proj_kernel<<<dim3(CC / 128, MM / 128), 256, 0, stream>>>(yb, WpT, b_proj, out);
}

// Round 3
// 229.642 us; speedup vs baseline: 1.0311x; 1.0267x over previous
//
#include <hip/hip_runtime.h>
#include <math.h>

// Problem constants (reference: B=4, T=2048, C=1024, H=16, d=64)
#define BB   4
#define TT   2048
#define CC   1024
#define HH   16
#define DD   64
#define MM   (BB*TT)     // 8192 rows
#define NQKV (3*CC)      // 3072
#define LCH  128         // attention chunk length
#define NCH  (TT/LCH)    // 16 chunks per (b,h)
#define EPSF 1e-6f

// LDS strides (in shorts) for attention kernels — padded to break bank aliasing
#define QKST 72          // Q/K tile row stride
#define PST  136         // P tile row stride
#define VTST 136         // V-transposed tile row stride

typedef __bf16 bf16x8 __attribute__((ext_vector_type(8)));
typedef float  floatx4 __attribute__((ext_vector_type(4)));

__device__ __forceinline__ unsigned short f2bf(float f) {
  union { float f; unsigned int u; } v; v.f = f;
  unsigned int r = v.u + 0x7fffu + ((v.u >> 16) & 1u); // RNE
  return (unsigned short)(r >> 16);
}
__device__ __forceinline__ float bf2f(unsigned short s) {
  union { unsigned int u; float f; } v; v.u = ((unsigned int)s) << 16;
  return v.f;
}
__device__ __forceinline__ float featmap(float v) {
  // elu(v)+1
  return v > 0.f ? v + 1.f : __expf(v);
}
// async global->LDS, 16B per lane; LDS dest = wave-uniform base + lane*16
__device__ __forceinline__ void gld_lds_b128(const unsigned short* g, unsigned short* l) {
  __builtin_amdgcn_global_load_lds(
      (const __attribute__((address_space(1))) unsigned int*)g,
      (__attribute__((address_space(3))) unsigned int*)l, 16, 0, 0);
}

// ---------------- prep: x->bf16 + both weight transposes, one kernel ----------------
__device__ __forceinline__ void transpose_cvt_body(const float* __restrict__ W,
                                                   unsigned short* __restrict__ out,
                                                   int R, int Cc, int bx32, int by32, int tid) {
  __shared__ float tile[32][33];
  int tx = tid & 31, ty = tid >> 5;  // 32 x 8
  int bx = bx32 * 32, by = by32 * 32;
  #pragma unroll
  for (int i = ty; i < 32; i += 8)
    tile[i][tx] = W[(size_t)(by + i) * Cc + bx + tx];
  __syncthreads();
  #pragma unroll
  for (int i = ty; i < 32; i += 8)
    out[(size_t)(bx + i) * R + by + tx] = f2bf(tile[tx][i]);
}

// grid: [0,8192) cvt_x | [8192,11264) W_attn transpose | [11264,12288) W_proj transpose
__global__ __launch_bounds__(256) void prep_kernel(
    const float* __restrict__ x, unsigned short* __restrict__ xb,
    const float* __restrict__ Wa, unsigned short* __restrict__ WaT,
    const float* __restrict__ Wp, unsigned short* __restrict__ WpT) {
  int blk = blockIdx.x, tid = threadIdx.x;
  if (blk < 8192) {
    int i = (blk * 256 + tid) * 4;
    float4 f = *(const float4*)(x + i);
    ushort4 o;
    o.x = f2bf(f.x); o.y = f2bf(f.y); o.z = f2bf(f.z); o.w = f2bf(f.w);
    *(ushort4*)(xb + i) = o;
  } else if (blk < 8192 + 3072) {
    int t = blk - 8192;                       // 96 x 32
    transpose_cvt_body(Wa, WaT, CC, NQKV, t % 96, t / 96, tid);
  } else {
    int t = blk - 11264;                      // 32 x 32
    transpose_cvt_body(Wp, WpT, CC, CC, t % 32, t / 32, tid);
  }
}

// ============== MFMA GEMM core: 128x128 tile, BK=64 (R6 known-good shape) ==========
// Used by gemm_proj (N=1024). Unchanged from the verified baseline.
#define GEMM_K_LOOP(A_, Bt_, K_)                                                 \
  __shared__ __align__(16) unsigned short As[128 * 64];                          \
  __shared__ __align__(16) unsigned short Bs[128 * 64];                          \
  int tid = threadIdx.x;                                                         \
  int wave = tid >> 6, lane = tid & 63;                                          \
  int lr = lane & 15, lq = lane >> 4;                                            \
  int m0 = blockIdx.y * 128, n0 = blockIdx.x * 128;                              \
  int wm = (wave >> 1) * 64, wn = (wave & 1) * 64;                               \
  int lrow = lane >> 3;                 /* 0..7: row within 8-row chunk */       \
  int lk = (lane & 7) ^ lrow;           /* swizzled source k-chunk */            \
  int rbase = wave * 32;                                                         \
  const unsigned short* gA = A_ + (size_t)(m0 + rbase + lrow) * K_ + lk * 8;     \
  const unsigned short* gB = Bt_ + (size_t)(n0 + rbase + lrow) * K_ + lk * 8;    \
  unsigned short* lA = As + rbase * 64;                                          \
  unsigned short* lB = Bs + rbase * 64;                                          \
  floatx4 acc[4][4] = {};                                                        \
  for (int k0 = 0; k0 < K_; k0 += 64) {                                          \
    __syncthreads(); /* prior frag reads done before overwrite */                \
    _Pragma("unroll")                                                            \
    for (int g = 0; g < 4; g++) {                                                \
      gld_lds_b128(gA + k0 + (size_t)g * 8 * K_, lA + g * 512);                  \
      gld_lds_b128(gB + k0 + (size_t)g * 8 * K_, lB + g * 512);                  \
    }                                                                            \
    __syncthreads(); /* staged data visible */                                   \
    _Pragma("unroll")                                                            \
    for (int kk = 0; kk < 2; kk++) {                                             \
      bf16x8 an[4], bm[4];                                                       \
      _Pragma("unroll")                                                          \
      for (int i = 0; i < 4; i++)                                                \
        an[i] = *(const bf16x8*)&Bs[(wn + i * 16 + lr) * 64 + ((((kk << 2) + lq) ^ (lr & 7)) << 3)]; \
      _Pragma("unroll")                                                          \
      for (int j = 0; j < 4; j++)                                                \
        bm[j] = *(const bf16x8*)&As[(wm + j * 16 + lr) * 64 + ((((kk << 2) + lq) ^ (lr & 7)) << 3)]; \
      _Pragma("unroll")                                                          \
      for (int i = 0; i < 4; i++)                                                \
        _Pragma("unroll")                                                        \
        for (int j = 0; j < 4; j++)                                              \
          acc[i][j] = __builtin_amdgcn_mfma_f32_16x16x32_bf16(an[i], bm[j], acc[i][j], 0, 0, 0); \
    }                                                                            \
  }

// ---------------- GEMM 1: qkv = x @ W_attn + b, split + feature map ----------------
// R11: BM=256 x BN=192, BK=32, 512 thr / 8 waves, 4-slot LDS ring (112 KiB),
// counted-vmcnt pipeline, MERGED single phase per K-tile:
//   {11 ds_read_b128 | stage A&B(t+3)} -> s_barrier -> lgkmcnt(0) ->
//   setprio(1) + 24 MFMA + setprio(0) -> vmcnt(6) -> s_barrier
// 2 barriers/K-tile (R10 had 4; sync overhead was ~2-3x MFMA issue time at
// MfmaUtil=30%). Ring-overwrite safety: stage(t+3)->slot(t-1) is issued after
// barrier#2(t-1), which every wave reaches only after its lgkmcnt(0) completed
// its slot(t-1) reads. Counted vmcnt(6) = 1.5 tiles in flight, drain 3->0 at tail.
// K summation order identical to baseline -> bitwise-identical results.
#define BKQ   32
#define ASLT  (256 * BKQ)   // 8192 shorts / slot
#define BSLT  (192 * BKQ)   // 6144 shorts / slot
#define NT_Q  (CC / BKQ)    // 32 K-tiles

__global__ __launch_bounds__(512, 2) void gemm_qkv_kernel(
    const unsigned short* __restrict__ A, const unsigned short* __restrict__ Bt,
    const float* __restrict__ bias,
    unsigned short* __restrict__ qh, unsigned short* __restrict__ kh,
    unsigned short* __restrict__ vh) {
  extern __shared__ __align__(16) unsigned short lds[];
  unsigned short* Ar = lds;                 // [4][256][32]
  unsigned short* Br = lds + 4 * ASLT;      // [4][192][32]

  const int tid = threadIdx.x;
  const int wave = tid >> 6, lane = tid & 63;
  const int lr = lane & 15, lq = lane >> 4;
  const int m0 = blockIdx.y * 256, n0 = blockIdx.x * 192;
  const int wm = (wave >> 2) * 128, wn = (wave & 3) * 48;

  // staging map: wave w covers rows [w*16, w*16+16) (+128 for the g1 load);
  // lane l -> row w*16 + (l>>2), LDS chunk l&3 (linear dest, 4 chunks x 8 shorts).
  // Global source chunk pre-swizzled: cs = (l&3) ^ ((row>>1)&3) = (l&3) ^ ((l>>3)&3).
  const int srow = wave * 16 + (lane >> 2);
  const int cs = (lane & 3) ^ ((lane >> 3) & 3);
  const unsigned short* gA0 = A  + (size_t)(m0 + srow) * CC + cs * 8;
  const unsigned short* gB0 = Bt + (size_t)(n0 + srow) * CC + cs * 8;
  unsigned short* const stA = Ar + wave * 512;   // wave-uniform LDS dest base
  unsigned short* const stB = Br + wave * 512;
  const bool bhi = (wave < 4);                   // waves 0-3 stage B rows 128..191

  // reader: global chunk lq at row r lives in LDS chunk lq ^ ((r>>1)&3);
  // r = frag_base + lr with frag_base % 16 == 0 -> (r>>1)&3 == (lr>>1)&3.
  const int chunk = lq ^ ((lr >> 1) & 3);
  const int roA = (wm + lr) * BKQ + chunk * 8;
  const int roB = (wn + lr) * BKQ + chunk * 8;

  floatx4 acc[3][8] = {};   // [n-frag][m-frag], transposed-C convention

#define QSTAGE_A(tt) do {                                      \
    const unsigned short* g_ = gA0 + (tt) * BKQ;               \
    unsigned short* d_ = stA + ((tt) & 3) * ASLT;              \
    gld_lds_b128(g_, d_);                                      \
    gld_lds_b128(g_ + (size_t)128 * CC, d_ + 4096);            \
  } while (0)
#define QSTAGE_B(tt) do {                                      \
    const unsigned short* g_ = gB0 + (tt) * BKQ;               \
    unsigned short* d_ = stB + ((tt) & 3) * BSLT;              \
    gld_lds_b128(g_, d_);                                      \
    if (bhi) gld_lds_b128(g_ + (size_t)128 * CC, d_ + 4096);   \
  } while (0)

  // prologue: stage K-tiles 0,1,2; wait tile 0 (keep tiles 1,2 in flight)
  QSTAGE_A(0); QSTAGE_B(0);
  QSTAGE_A(1); QSTAGE_B(1);
  QSTAGE_A(2); QSTAGE_B(2);
  asm volatile("s_waitcnt vmcnt(6)" ::: "memory");
  __builtin_amdgcn_s_barrier();

  #pragma unroll 4
  for (int t = 0; t < NT_Q; ++t) {
    const unsigned short* sA = Ar + (t & 3) * ASLT + roA;
    const unsigned short* sB = Br + (t & 3) * BSLT + roB;
    bf16x8 an[3], bm[8];
    #pragma unroll
    for (int i = 0; i < 3; i++) an[i] = *(const bf16x8*)(sB + i * (16 * BKQ));
    #pragma unroll
    for (int j = 0; j < 8; j++) bm[j] = *(const bf16x8*)(sA + j * (16 * BKQ));
    if (t < NT_Q - 3) { QSTAGE_A(t + 3); QSTAGE_B(t + 3); }
    __builtin_amdgcn_s_barrier();
    asm volatile("s_waitcnt lgkmcnt(0)" ::: "memory");
    __builtin_amdgcn_s_setprio(1);
    #pragma unroll
    for (int i = 0; i < 3; i++)
      #pragma unroll
      for (int j = 0; j < 8; j++)
        acc[i][j] = __builtin_amdgcn_mfma_f32_16x16x32_bf16(an[i], bm[j], acc[i][j], 0, 0, 0);
    __builtin_amdgcn_s_setprio(0);
    // boundary: next tile's data must be resident; counted (never 0 until drain)
    if (t < NT_Q - 3)        asm volatile("s_waitcnt vmcnt(6)" ::: "memory");
    else if (t == NT_Q - 3)  asm volatile("s_waitcnt vmcnt(3)" ::: "memory");
    else if (t == NT_Q - 2)  asm volatile("s_waitcnt vmcnt(0)" ::: "memory");
    __builtin_amdgcn_s_barrier();
  }
#undef QSTAGE_A
#undef QSTAGE_B

  // epilogue: transposed C/D -> lane holds 4 consecutive n (channels), m = col.
  // BN=192 crosses q/k/v 1024-boundaries -> select dst per i-frag (static unroll).
  // j outer / i inner so both 32B halves of an output line are written adjacently.
  unsigned short* dstv[3];
  size_t qoff[3];
  float4 bi[3];
  bool feat[3];
  #pragma unroll
  for (int i = 0; i < 3; i++) {
    const int n = n0 + wn + i * 16 + lq * 4;
    dstv[i] = (n < 1024) ? qh : (n < 2048) ? kh : vh;
    feat[i] = (n < 2048);
    const int h = (n & 1023) >> 6, dd = n & 63;
    qoff[i] = (size_t)h * (TT * DD) + dd;
    bi[i] = *(const float4*)&bias[n];
  }
  #pragma unroll
  for (int j = 0; j < 8; j++) {
    const int m = m0 + wm + j * 16 + lr;
    const int b = m >> 11, tg = m & 2047;
    const size_t pj = (size_t)b * (HH * TT * DD) + (size_t)tg * DD;
    #pragma unroll
    for (int i = 0; i < 3; i++) {
      float v0 = acc[i][j][0] + bi[i].x, v1 = acc[i][j][1] + bi[i].y;
      float v2 = acc[i][j][2] + bi[i].z, v3 = acc[i][j][3] + bi[i].w;
      if (feat[i]) { v0 = featmap(v0); v1 = featmap(v1); v2 = featmap(v2); v3 = featmap(v3); }
      ushort4 o; o.x = f2bf(v0); o.y = f2bf(v1); o.z = f2bf(v2); o.w = f2bf(v3);
      *(ushort4*)&dstv[i][pj + qoff[i]] = o;
    }
  }
}

// ---------------- GEMM 2: out = y @ W_proj + b_proj (fp32 out) ----------------
__global__ __launch_bounds__(256) void gemm_proj_kernel(
    const unsigned short* __restrict__ A, const unsigned short* __restrict__ Bt,
    const float* __restrict__ bias, float* __restrict__ out) {
  GEMM_K_LOOP(A, Bt, CC)
  #pragma unroll
  for (int i = 0; i < 4; i++) {
    int n = n0 + wn + i * 16 + lq * 4;
    float4 bi = *(const float4*)&bias[n];
    #pragma unroll
    for (int j = 0; j < 4; j++) {
      int m = m0 + wm + j * 16 + lr;
      float4 o;
      o.x = acc[i][j][0] + bi.x; o.y = acc[i][j][1] + bi.y;
      o.z = acc[i][j][2] + bi.z; o.w = acc[i][j][3] + bi.w;
      *(float4*)&out[(size_t)m * CC + n] = o;
    }
  }
}

// ---------------- Phase A: per-chunk KV state (MFMA) ----------------
// grid: B*H*NCH blocks, 256 threads.
// KVx[blk][80][64] fp32, stored TRANSPOSED: KVx[j][i] = (K_c^T V_ext)[i][j],
// where V_ext = [V | ones | 0...] so col 64 is ksum. Rows 65..79 are zero.
__global__ __launch_bounds__(256) void chunk_state_kernel(
    const unsigned short* __restrict__ kh, const unsigned short* __restrict__ vh,
    float* __restrict__ KVx) {
  __shared__ __align__(16) unsigned short Kt[64 * VTST];   // K^T: Kt[i][t]
  __shared__ __align__(16) unsigned short Vt[80 * VTST];   // V^T + ones/zero rows
  int blk = blockIdx.x;
  int bh = blk / NCH, c = blk % NCH;
  int tid = threadIdx.x;
  const unsigned short* kp = kh + ((size_t)bh * TT + c * LCH) * DD;
  const unsigned short* vp = vh + ((size_t)bh * TT + c * LCH) * DD;
  {
    int t = tid & 127;
    for (int j8 = (tid >> 7) * 8; j8 < DD; j8 += 16) {
      union { uint4 u; unsigned short s[8]; } wk, wv;
      wk.u = *(const uint4*)&kp[(size_t)t * DD + j8];
      wv.u = *(const uint4*)&vp[(size_t)t * DD + j8];
      #pragma unroll
      for (int jj = 0; jj < 8; jj++) {
        Kt[(j8 + jj) * VTST + t] = wk.s[jj];
        Vt[(j8 + jj) * VTST + t] = wv.s[jj];
      }
    }
  }
  for (int e = tid; e < 16 * 128; e += 256) {
    int rr = e >> 7, n = e & 127;
    Vt[(64 + rr) * VTST + n] = (rr == 0) ? (unsigned short)0x3F80 : (unsigned short)0;
  }
  __syncthreads();
  int wave = tid >> 6, lane = tid & 63;
  int lr = lane & 15, lq = lane >> 4;
  int i0 = wave * 16;             // wave's 16-row band of K^T (i dimension)
  floatx4 acc[5] = {};
  #pragma unroll
  for (int kk = 0; kk < 4; kk++) {
    bf16x8 a = *(const bf16x8*)&Kt[(i0 + lr) * VTST + kk * 32 + lq * 8];
    #pragma unroll
    for (int jt = 0; jt < 5; jt++) {
      bf16x8 b = *(const bf16x8*)&Vt[(jt * 16 + lr) * VTST + kk * 32 + lq * 8];
      acc[jt] = __builtin_amdgcn_mfma_f32_16x16x32_bf16(a, b, acc[jt], 0, 0, 0);
    }
  }
  // C/D: col(j) = lane&15, row(i) = i0 + lq*4 + r; store transposed [j][i].
  float* o = KVx + (size_t)blk * 5120;
  #pragma unroll
  for (int jt = 0; jt < 5; jt++)
    *(float4*)&o[(jt * 16 + lr) * 64 + i0 + lq * 4] = *(float4*)&acc[jt];
}

// ---------------- Phase B: exclusive prefix over chunks -> bf16 SP_ext ----------
// R11: fully unrolled — all 16 chunk loads issued up front (16 float4 = 64 VGPR
// in flight per thread), then the serial scan+stores. Removes 16 serial HBM
// round-trips at 5-waves/CU occupancy.
__global__ __launch_bounds__(256) void prefix_state_kernel(const float* __restrict__ KVx,
                                                           unsigned short* __restrict__ SPb) {
  int bh = blockIdx.x / 5, jb = blockIdx.x % 5;
  int e = jb * 1024 + threadIdx.x * 4;
  size_t base0 = ((size_t)bh * NCH) * 5120 + e;
  float4 v[NCH];
  #pragma unroll
  for (int c = 0; c < NCH; c++)
    v[c] = *(const float4*)&KVx[base0 + (size_t)c * 5120];
  float r0 = 0.f, r1 = 0.f, r2 = 0.f, r3 = 0.f;
  #pragma unroll
  for (int c = 0; c < NCH; c++) {
    ushort4 o;
    o.x = f2bf(r0); o.y = f2bf(r1); o.z = f2bf(r2); o.w = f2bf(r3);
    *(ushort4*)&SPb[base0 + (size_t)c * 5120] = o;
    r0 += v[c].x; r1 += v[c].y; r2 += v[c].z; r3 += v[c].w;
  }
}

// ---------------- Phase C: per-chunk attention output (MFMA, transposed) ----------
// R11: setprio REMOVED (R10 post-mortem: 4-wave barrier-synced blocks are the
// m190 lockstep regime — setprio cost ~7 µs total, not the m191 regime).
__global__ __launch_bounds__(256) void chunk_attn_kernel(
    const unsigned short* __restrict__ qh, const unsigned short* __restrict__ kh,
    const unsigned short* __restrict__ vh, const unsigned short* __restrict__ SPb,
    unsigned short* __restrict__ yb) {
  // region A: Qs[128][72] + Ks[128][72] = 18432 shorts, reused as P[128][136] = 17408
  // region B: Vt[80][136] = 10880 shorts
  __shared__ __align__(16) unsigned short lds[128 * QKST * 2 + 80 * VTST];  // 58624 B
  unsigned short* Qs = lds;                       // [128][QKST]
  unsigned short* Ks = lds + 128 * QKST;          // [128][QKST]
  unsigned short* P  = lds;                       // [128][PST] (after Qs/Ks dead)
  unsigned short* Vt = lds + 128 * QKST * 2;      // [80][VTST]

  int blk = blockIdx.x;
  int bh = blk / NCH, c = blk % NCH;
  int b = bh / HH, h = bh % HH;
  int tid = threadIdx.x;
  const unsigned short* qp = qh + ((size_t)bh * TT + c * LCH) * DD;
  const unsigned short* kp = kh + ((size_t)bh * TT + c * LCH) * DD;
  const unsigned short* vp = vh + ((size_t)bh * TT + c * LCH) * DD;

  // stage Q, K (row-major, padded stride)
  for (int e = tid; e < 1024; e += 256) {
    int row = e >> 3, k8 = (e & 7) * 8;
    *(uint4*)&Qs[row * QKST + k8] = *(const uint4*)&qp[(size_t)row * DD + k8];
    *(uint4*)&Ks[row * QKST + k8] = *(const uint4*)&kp[(size_t)row * DD + k8];
  }
  // stage V transposed: Vt[j][t] = V[t][j]
  {
    int t = tid & 127;
    for (int j8 = (tid >> 7) * 8; j8 < DD; j8 += 16) {
      union { uint4 u; unsigned short s[8]; } w;
      w.u = *(const uint4*)&vp[(size_t)t * DD + j8];
      #pragma unroll
      for (int jj = 0; jj < 8; jj++) Vt[(j8 + jj) * VTST + t] = w.s[jj];
    }
  }
  // ones row (j=64) and zero rows (65..79)
  for (int e = tid; e < 16 * 128; e += 256) {
    int rr = e >> 7, n = e & 127;
    Vt[(64 + rr) * VTST + n] = (rr == 0) ? (unsigned short)0x3F80 : (unsigned short)0;
  }
  __syncthreads();

  int wave = tid >> 6, lane = tid & 63;
  int lr = lane & 15, lq = lane >> 4;
  int mbase = wave * 32;

  // Q frags for this wave's two 16-row t-tiles (A-op for QK, B-op for QSP)
  bf16x8 aq[2][2];
  #pragma unroll
  for (int i = 0; i < 2; i++)
    #pragma unroll
    for (int kk = 0; kk < 2; kk++)
      aq[i][kk] = *(const bf16x8*)&Qs[(mbase + i * 16 + lr) * QKST + kk * 32 + lq * 8];

  // accT[jt][it]: D[j][t], rows j = jt*16 + lq*4 + r, cols t = mbase + it*16 + lr
  floatx4 accT[5][2] = {};
  // inter-chunk (transposed): accT += SP_ext^T-matmul: A = SPb rows [j][i], B = Q rows [t][i]
  const unsigned short* spb = SPb + (size_t)blk * (80 * 64);
  #pragma unroll
  for (int jt = 0; jt < 5; jt++)
    #pragma unroll
    for (int kk = 0; kk < 2; kk++) {
      bf16x8 asp = *(const bf16x8*)&spb[(jt * 16 + lr) * 64 + kk * 32 + lq * 8];
      accT[jt][0] = __builtin_amdgcn_mfma_f32_16x16x32_bf16(asp, aq[0][kk], accT[jt][0], 0, 0, 0);
      accT[jt][1] = __builtin_amdgcn_mfma_f32_16x16x32_bf16(asp, aq[1][kk], accT[jt][1], 0, 0, 0);
    }
  // intra-chunk scores: S = Q @ K^T (row=t(q), col=t'(k))
  floatx4 sacc[2][8] = {};
  #pragma unroll
  for (int nt = 0; nt < 8; nt++)
    #pragma unroll
    for (int kk = 0; kk < 2; kk++) {
      bf16x8 bk = *(const bf16x8*)&Ks[(nt * 16 + lr) * QKST + kk * 32 + lq * 8];
      sacc[0][nt] = __builtin_amdgcn_mfma_f32_16x16x32_bf16(aq[0][kk], bk, sacc[0][nt], 0, 0, 0);
      sacc[1][nt] = __builtin_amdgcn_mfma_f32_16x16x32_bf16(aq[1][kk], bk, sacc[1][nt], 0, 0, 0);
    }
  __syncthreads();  // everyone done reading Qs/Ks before P overwrites them

  // causal mask + bf16 round, C-layout -> LDS P[t][t']
  #pragma unroll
  for (int i = 0; i < 2; i++)
    #pragma unroll
    for (int nt = 0; nt < 8; nt++) {
      int col = nt * 16 + lr;
      #pragma unroll
      for (int r = 0; r < 4; r++) {
        int m = mbase + i * 16 + lq * 4 + r;
        float v = (col <= m) ? sacc[i][nt][r] : 0.f;
        P[m * PST + col] = f2bf(v);
      }
    }
  __syncthreads();

  // accT += (P @ V_ext)^T: A = Vt rows [j][t'], B = P rows [t][t']
  #pragma unroll
  for (int kk4 = 0; kk4 < 4; kk4++) {
    bf16x8 bp0 = *(const bf16x8*)&P[(mbase + lr) * PST + kk4 * 32 + lq * 8];
    bf16x8 bp1 = *(const bf16x8*)&P[(mbase + 16 + lr) * PST + kk4 * 32 + lq * 8];
    #pragma unroll
    for (int jt = 0; jt < 5; jt++) {
      bf16x8 av = *(const bf16x8*)&Vt[(jt * 16 + lr) * VTST + kk4 * 32 + lq * 8];
      accT[jt][0] = __builtin_amdgcn_mfma_f32_16x16x32_bf16(av, bp0, accT[jt][0], 0, 0, 0);
      accT[jt][1] = __builtin_amdgcn_mfma_f32_16x16x32_bf16(av, bp1, accT[jt][1], 0, 0, 0);
    }
  }

  // epilogue: den = row 64 = accT[4][it] reg0 on lanes lq=0, col=t=lane&15.
  #pragma unroll
  for (int it = 0; it < 2; it++) {
    float den = __shfl(accT[4][it][0], lr, 64);
    float inv = 1.f / (den + EPSF);
    int tg = c * LCH + mbase + it * 16 + lr;
    size_t base = ((size_t)b * TT + tg) * CC + h * DD;
    #pragma unroll
    for (int jt = 0; jt < 4; jt++) {
      ushort4 o;
      o.x = f2bf(accT[jt][it][0] * inv);
      o.y = f2bf(accT[jt][it][1] * inv);
      o.z = f2bf(accT[jt][it][2] * inv);
      o.w = f2bf(accT[jt][it][3] * inv);
      *(ushort4*)&yb[base + jt * 16 + lq * 4] = o;
    }
  }
}

// ---------------- host launch ----------------
extern "C" void kernel_launch(void* const* d_in, const int* in_sizes, int n_in,
                              void* d_out, int out_size, void* d_ws, size_t ws_size,
                              hipStream_t stream) {
  const float* x      = (const float*)d_in[0];
  const float* W_attn = (const float*)d_in[1];
  const float* b_attn = (const float*)d_in[2];
  const float* W_proj = (const float*)d_in[3];
  const float* b_proj = (const float*)d_in[4];
  float* out = (float*)d_out;

  char* ws = (char*)d_ws;
  size_t off = 0;
  auto alloc = [&](size_t bytes) -> char* {
    char* p = ws + off;
    off += (bytes + 255) & ~(size_t)255;
    return p;
  };
  unsigned short* xb  = (unsigned short*)alloc((size_t)MM * CC * 2);   // reused as yb
  unsigned short* WaT = (unsigned short*)alloc((size_t)NQKV * CC * 2);
  unsigned short* WpT = (unsigned short*)alloc((size_t)CC * CC * 2);
  unsigned short* qh  = (unsigned short*)alloc((size_t)MM * CC * 2);
  unsigned short* kh  = (unsigned short*)alloc((size_t)MM * CC * 2);
  unsigned short* vh  = (unsigned short*)alloc((size_t)MM * CC * 2);
  float* KVx = (float*)alloc((size_t)BB * HH * NCH * 80 * 64 * 4);
  unsigned short* SPb = (unsigned short*)alloc((size_t)BB * HH * NCH * 80 * 64 * 2);
  unsigned short* yb = xb;  // xb dead after gemm_qkv

  static bool s_attr_done = false;
  if (!s_attr_done) {
    (void)hipFuncSetAttribute((const void*)gemm_qkv_kernel,
                              hipFuncAttributeMaxDynamicSharedMemorySize, 114688);
    s_attr_done = true;
  }

  prep_kernel<<<12288, 256, 0, stream>>>(x, xb, W_attn, WaT, W_proj, WpT);
  gemm_qkv_kernel<<<dim3(NQKV / 192, MM / 256), 512, 114688, stream>>>(xb, WaT, b_attn, qh, kh, vh);
  chunk_state_kernel<<<BB * HH * NCH, 256, 0, stream>>>(kh, vh, KVx);
  prefix_state_kernel<<<BB * HH * 5, 256, 0, stream>>>(KVx, SPb);
  chunk_attn_kernel<<<BB * HH * NCH, 256, 0, stream>>>(qh, kh, vh, SPb, yb);
  gemm_proj_kernel<<<dim3(CC / 128, MM / 128), 256, 0, stream>>>(yb, WpT, b_proj, out);
}